// Round 13
// baseline (1303.432 us; speedup 1.0000x reference)
//
#include <hip/hip_runtime.h>
#include <stdint.h>

#define T_SEQ 2048
#define HIDN  4096
#define NH    32
#define NKV   8
#define DH    128
#define INTER 14336
#define QKV_N 6144   /* (32+16)*128 */
#define EPSR  1e-5f
#define SCALE 0.08838834764831845f  /* 1/sqrt(128) */
#define KVB   64

typedef __bf16 bf16x8 __attribute__((ext_vector_type(8)));
typedef float  f32x4  __attribute__((ext_vector_type(4)));

__device__ __forceinline__ f32x4 mfma16(bf16x8 a, bf16x8 b, f32x4 c) {
  return __builtin_amdgcn_mfma_f32_16x16x32_bf16(a, b, c, 0, 0, 0);
}

__device__ __forceinline__ void glds16(const void* g, void* l) {
  __builtin_amdgcn_global_load_lds(
      (__attribute__((address_space(1))) void*)g,
      (__attribute__((address_space(3))) void*)l,
      16, 0, 0);
}

// ====== merged weight convert: wqkv | wo | w13(interleaved) | w2, one kernel ======
__global__ __launch_bounds__(256) void cvt_all_kernel(
    const float* __restrict__ wqkv, const float* __restrict__ wo,
    const float* __restrict__ w1, const float* __restrict__ w3,
    const float* __restrict__ w2, __bf16* __restrict__ dst) {
  const long E0 = (long)QKV_N * HIDN;            // 25,165,824
  const long E1 = E0 + (long)HIDN * HIDN;        // 41,943,040
  const long E2 = E1 + 2L * INTER * HIDN;        // 159,383,552
  const long E3 = E2 + (long)HIDN * INTER;       // 218,103,808
  long stride = (long)gridDim.x * 256 * 16;
  for (long f = ((long)blockIdx.x * 256 + threadIdx.x) * 16; f < E3; f += stride) {
    const float* src;
    if (f < E0) {
      src = wqkv + f;
    } else if (f < E1) {
      src = wo + (f - E0);
    } else if (f < E2) {
      long l = f - E1;
      int c = (int)(l >> 12), i = (int)(l & 4095);
      int tau = c >> 8, j2 = c & 255;
      int wn = j2 >> 6, j = j2 & 63, nt = j >> 4, k16 = j & 15;
      src = (nt < 2 ? w1 : w3) +
            (size_t)(tau * 128 + wn * 32 + (nt & 1) * 16 + k16) * HIDN + i;
    } else {
      src = w2 + (f - E2);
    }
    float4 a = *(const float4*)(src);
    float4 b = *(const float4*)(src + 4);
    float4 e = *(const float4*)(src + 8);
    float4 g = *(const float4*)(src + 12);
    bf16x8 o0, o1;
    o0[0]=(__bf16)a.x; o0[1]=(__bf16)a.y; o0[2]=(__bf16)a.z; o0[3]=(__bf16)a.w;
    o0[4]=(__bf16)b.x; o0[5]=(__bf16)b.y; o0[6]=(__bf16)b.z; o0[7]=(__bf16)b.w;
    o1[0]=(__bf16)e.x; o1[1]=(__bf16)e.y; o1[2]=(__bf16)e.z; o1[3]=(__bf16)e.w;
    o1[4]=(__bf16)g.x; o1[5]=(__bf16)g.y; o1[6]=(__bf16)g.z; o1[7]=(__bf16)g.w;
    *(bf16x8*)(dst + f) = o0;
    *(bf16x8*)(dst + f + 8) = o1;
  }
}

// ---------------- RMSNorm: fp32 in -> bf16 out ----------------
__global__ __launch_bounds__(256) void rmsnorm_kernel(
    const float* __restrict__ x, const float* __restrict__ w,
    __bf16* __restrict__ y) {
  const int row = blockIdx.x, tid = threadIdx.x;
  const float* xr = x + (size_t)row * HIDN + tid * 16;
  float4 v0 = ((const float4*)xr)[0];
  float4 v1 = ((const float4*)xr)[1];
  float4 v2 = ((const float4*)xr)[2];
  float4 v3 = ((const float4*)xr)[3];
  float ss = v0.x*v0.x + v0.y*v0.y + v0.z*v0.z + v0.w*v0.w
           + v1.x*v1.x + v1.y*v1.y + v1.z*v1.z + v1.w*v1.w
           + v2.x*v2.x + v2.y*v2.y + v2.z*v2.z + v2.w*v2.w
           + v3.x*v3.x + v3.y*v3.y + v3.z*v3.z + v3.w*v3.w;
  #pragma unroll
  for (int off = 32; off >= 1; off >>= 1) ss += __shfl_xor(ss, off, 64);
  __shared__ float red[4];
  if ((tid & 63) == 0) red[tid >> 6] = ss;
  __syncthreads();
  float rn = rsqrtf((red[0] + red[1] + red[2] + red[3]) * (1.0f / HIDN) + EPSR);
  const float* wr = w + tid * 16;
  #pragma unroll
  for (int h = 0; h < 2; h++) {
    float4 a = ((const float4*)xr)[h*2], b = ((const float4*)xr)[h*2+1];
    float4 wa = ((const float4*)wr)[h*2], wb = ((const float4*)wr)[h*2+1];
    bf16x8 o;
    o[0]=(__bf16)(a.x*rn*wa.x); o[1]=(__bf16)(a.y*rn*wa.y);
    o[2]=(__bf16)(a.z*rn*wa.z); o[3]=(__bf16)(a.w*rn*wa.w);
    o[4]=(__bf16)(b.x*rn*wb.x); o[5]=(__bf16)(b.y*rn*wb.y);
    o[6]=(__bf16)(b.z*rn*wb.z); o[7]=(__bf16)(b.w*rn*wb.w);
    *(bf16x8*)(y + (size_t)row * HIDN + tid * 16 + h * 8) = o;
  }
}

// ---- fused: h = p0+p1+resid (f32 out) ; xn = rmsnorm(h)*w (bf16 out) ----
__global__ __launch_bounds__(256) void add3_rms_kernel(
    const float* __restrict__ p, const float* __restrict__ resid,
    const float* __restrict__ w, float* __restrict__ hout,
    __bf16* __restrict__ xn) {
  const int row = blockIdx.x, tid = threadIdx.x;
  const size_t base = (size_t)row * HIDN + tid * 16;
  const size_t half = (size_t)T_SEQ * HIDN;
  float h[16];
  float ss = 0.f;
  #pragma unroll
  for (int q = 0; q < 4; q++) {
    float4 a = *(const float4*)(p + base + q * 4);
    float4 b = *(const float4*)(p + half + base + q * 4);
    float4 c = *(const float4*)(resid + base + q * 4);
    h[q*4+0] = a.x + b.x + c.x; h[q*4+1] = a.y + b.y + c.y;
    h[q*4+2] = a.z + b.z + c.z; h[q*4+3] = a.w + b.w + c.w;
    ss += h[q*4]*h[q*4] + h[q*4+1]*h[q*4+1] + h[q*4+2]*h[q*4+2] + h[q*4+3]*h[q*4+3];
    *(float4*)(hout + base + q * 4) = *(float4*)&h[q*4];
  }
  #pragma unroll
  for (int off = 32; off >= 1; off >>= 1) ss += __shfl_xor(ss, off, 64);
  __shared__ float red[4];
  if ((tid & 63) == 0) red[tid >> 6] = ss;
  __syncthreads();
  float rn = rsqrtf((red[0] + red[1] + red[2] + red[3]) * (1.0f / HIDN) + EPSR);
  #pragma unroll
  for (int hb = 0; hb < 2; hb++) {
    bf16x8 o;
    #pragma unroll
    for (int e = 0; e < 8; e++) {
      float wv = w[tid * 16 + hb * 8 + e];
      o[e] = (__bf16)(h[hb*8+e] * rn * wv);
    }
    *(bf16x8*)(xn + base + hb * 8) = o;
  }
}

// ====== 256x256 GEMM v3: BK=32, 5-deep LDS ring (160KB), phase-split MFMA, ======
// pipelined fragment reads, vmcnt(8) ONCE per K-tile (775-cyc prefetch slack).
// 512 thr / 8 waves (2Mx4N), wave tile 128x64, 32 MFMA per K-tile = 2 phases.
// Per tile t: P0{LDA4(af1,buf t); STAGE_AB(t+4); lgkm(4); 16 MFMA(mb0); bar}
//             P1{LDA4(af0',buf t+1)+LDB4(bf'); lgkm(8); 16 MFMA(mb4); vmcnt(8); bar}
// Ledger: VMW(8) at P1 of tau allows {AB(tau+4),AB(tau+3)}, forces AB(tau+2) ->
// buf(tau+1) reads (1 phase later) covered; stage->force = 5 phases (~775cyc).
// Tail: VMW(4)/VMW(0) on last 4 tiles. E/O register parity avoids WAR.
// EPI: 0 = f32 partial at Cout + z*M*N; 1 = bf16; 2 = silu(u)*v (W13, Nout=N/2)
template<int EPI>
__global__ __launch_bounds__(512, 2) void gemm256_kernel(
    const __bf16* __restrict__ A, const __bf16* __restrict__ B,
    void* __restrict__ Cout, int M, int N, int Kfull, int KZ, int Nout) {
  extern __shared__ __align__(16) char smem[];
  const int tid = threadIdx.x;
  const int lane = tid & 63;
  const int wv = tid >> 6;        // 0..7
  const int wm = wv >> 2;         // 0..1
  const int wn = wv & 3;          // 0..3
  const int lr = lane & 15, ql = lane >> 4;

  const int gx = gridDim.x, gy = gridDim.y;
  const int nwg = gx * gy;
  const int orig = blockIdx.y * gx + blockIdx.x;
  const int cpx = nwg >> 3;
  const int swz = (orig & 7) * cpx + (orig >> 3);
  const int by = swz % gy, bx = swz / gy;
  const int m0 = by * 256, n0 = bx * 256;
  const int kbase = blockIdx.z * KZ;
  const int NT = KZ >> 5;                  // BK=32 tiles (even, >=8)

  // staging addresses: 1024 16B units -> A[256 rows][4 slots]; B at +16384
  const int u0 = tid, u1 = tid + 512;
  const int r0 = u0 >> 2, r1 = u1 >> 2;
  const int p0 = (u0 & 3) ^ ((r0 >> 1) & 3);
  const int p1 = (u1 & 3) ^ ((r1 >> 1) & 3);
  const char* aR0 = (const char*)(A + (size_t)(m0 + r0) * Kfull + kbase) + p0 * 16;
  const char* aR1 = (const char*)(A + (size_t)(m0 + r1) * Kfull + kbase) + p1 * 16;
  const char* bR0 = (const char*)(B + (size_t)(n0 + r0) * Kfull + kbase) + p0 * 16;
  const char* bR1 = (const char*)(B + (size_t)(n0 + r1) * Kfull + kbase) + p1 * 16;
  const int d0 = u0 * 16, d1 = u1 * 16;

  const int sA = ql ^ ((lr >> 1) & 3);
  int aoff[8], boff[4];
  #pragma unroll
  for (int mt = 0; mt < 8; mt++) aoff[mt] = (wm * 128 + mt * 16 + lr) * 64 + sA * 16;
  #pragma unroll
  for (int nt = 0; nt < 4; nt++) boff[nt] = 16384 + (wn * 64 + nt * 16 + lr) * 64 + sA * 16;

#define STAGE_AB(t, b) do {                                            \
    const size_t _o = (size_t)(t) * 64;                                \
    char* _d = smem + (b) * 32768;                                     \
    glds16(aR0 + _o, _d + d0);                                         \
    glds16(aR1 + _o, _d + d1);                                         \
    glds16(bR0 + _o, _d + 16384 + d0);                                 \
    glds16(bR1 + _o, _d + 16384 + d1);                                 \
  } while (0)
#define LDA4(dst, mb, b) do {                                          \
    const char* _p = smem + (b) * 32768;                               \
    dst[0] = *(const bf16x8*)(_p + aoff[(mb) + 0]);                    \
    dst[1] = *(const bf16x8*)(_p + aoff[(mb) + 1]);                    \
    dst[2] = *(const bf16x8*)(_p + aoff[(mb) + 2]);                    \
    dst[3] = *(const bf16x8*)(_p + aoff[(mb) + 3]);                    \
  } while (0)
#define LDB4(dst, b) do {                                              \
    const char* _p = smem + (b) * 32768;                               \
    dst[0] = *(const bf16x8*)(_p + boff[0]);                           \
    dst[1] = *(const bf16x8*)(_p + boff[1]);                           \
    dst[2] = *(const bf16x8*)(_p + boff[2]);                           \
    dst[3] = *(const bf16x8*)(_p + boff[3]);                           \
  } while (0)
#define VMW(n)  asm volatile("s_waitcnt vmcnt(" #n ")" ::: "memory")
#define BAR()   __builtin_amdgcn_s_barrier()
#define LGKM(n) do { asm volatile("s_waitcnt lgkmcnt(" #n ")" ::: "memory"); \
    __builtin_amdgcn_sched_barrier(0); } while (0)
#define MFMA16(mb, AF, BF) do {                                        \
    __builtin_amdgcn_s_setprio(1);                                     \
    _Pragma("unroll") for (int _m = 0; _m < 4; _m++)                   \
      _Pragma("unroll") for (int _n = 0; _n < 4; _n++)                 \
        acc[(mb) + _m][_n] = mfma16(AF[_m], BF[_n], acc[(mb) + _m][_n]); \
    __builtin_amdgcn_s_setprio(0);                                     \
  } while (0)
#define INC5(v) v = (v == 4) ? 0 : v + 1

  f32x4 acc[8][4] = {};
  bf16x8 af0E[4], af0O[4], af1[4], bfE[4], bfO[4];

  // prologue: stage tiles 0..3 into bufs 0..3 (16 loads); tile 0 forced ready
  STAGE_AB(0, 0); STAGE_AB(1, 1); STAGE_AB(2, 2); STAGE_AB(3, 3);
  VMW(12);
  BAR();
  LDA4(af0E, 0, 0); LDB4(bfE, 0);

  int bc = 0, bn = 1, sb = 4;
  for (int t = 0; t < NT - 4; t += 2) {
    // ---- tile t (even parity)
    LDA4(af1, 4, bc);
    STAGE_AB(t + 4, sb);
    LGKM(4);
    MFMA16(0, af0E, bfE);
    BAR();
    LDA4(af0O, 0, bn); LDB4(bfO, bn);
    LGKM(8);
    MFMA16(4, af1, bfE);
    VMW(8); BAR();
    bc = bn; INC5(bn); INC5(sb);
    // ---- tile t+1 (odd parity)
    LDA4(af1, 4, bc);
    STAGE_AB(t + 5, sb);
    LGKM(4);
    MFMA16(0, af0O, bfO);
    BAR();
    LDA4(af0E, 0, bn); LDB4(bfE, bn);
    LGKM(8);
    MFMA16(4, af1, bfO);
    VMW(8); BAR();
    bc = bn; INC5(bn); INC5(sb);
  }
  // ---- tail: tiles NT-4..NT-1 (E,O,E,O), no staging
  // tile NT-4 (E)
  LDA4(af1, 4, bc);
  LGKM(4); MFMA16(0, af0E, bfE); BAR();
  LDA4(af0O, 0, bn); LDB4(bfO, bn);
  LGKM(8); MFMA16(4, af1, bfE);
  VMW(4); BAR();
  bc = bn; INC5(bn);
  // tile NT-3 (O)
  LDA4(af1, 4, bc);
  LGKM(4); MFMA16(0, af0O, bfO); BAR();
  LDA4(af0E, 0, bn); LDB4(bfE, bn);
  LGKM(8); MFMA16(4, af1, bfO);
  VMW(0); BAR();
  bc = bn; INC5(bn);
  // tile NT-2 (E)
  LDA4(af1, 4, bc);
  LGKM(4); MFMA16(0, af0E, bfE); BAR();
  LDA4(af0O, 0, bn); LDB4(bfO, bn);
  LGKM(8); MFMA16(4, af1, bfE); BAR();
  bc = bn;
  // tile NT-1 (O)
  LDA4(af1, 4, bc);
  LGKM(4); MFMA16(0, af0O, bfO); BAR();
  LGKM(0); MFMA16(4, af1, bfO);

#undef STAGE_AB
#undef LDA4
#undef LDB4
#undef VMW
#undef BAR
#undef LGKM
#undef MFMA16
#undef INC5

  // epilogue
  #pragma unroll
  for (int mt = 0; mt < 8; mt++) {
    #pragma unroll
    for (int r = 0; r < 4; r++) {
      int rr = m0 + wm * 128 + mt * 16 + ql * 4 + r;
      if (EPI == 2) {
        #pragma unroll
        for (int nt = 0; nt < 2; nt++) {
          float u = acc[mt][nt][r];
          float v = acc[mt][nt + 2][r];
          float g = u / (1.0f + __expf(-u)) * v;
          int cc = (n0 >> 1) + wn * 32 + nt * 16 + lr;
          ((__bf16*)Cout)[(size_t)rr * Nout + cc] = (__bf16)g;
        }
      } else {
        #pragma unroll
        for (int nt = 0; nt < 4; nt++) {
          int cc = n0 + wn * 64 + nt * 16 + lr;
          size_t ix = (size_t)rr * N + cc;
          float val = acc[mt][nt][r];
          if (EPI == 0) ((float*)Cout)[(size_t)blockIdx.z * M * N + ix] = val;
          else          ((__bf16*)Cout)[ix] = (__bf16)val;
        }
      }
    }
  }
}

// ---------------- split-K combine: out = p[0] + p[1] + resid ----------------
__global__ __launch_bounds__(256) void add3_kernel(
    const float* __restrict__ p, const float* __restrict__ r,
    float* __restrict__ o, long n) {
  long stride = (long)gridDim.x * 1024;
  for (long i = ((long)blockIdx.x * 256 + threadIdx.x) * 4; i < n; i += stride) {
    float4 a = *(const float4*)(p + i);
    float4 b = *(const float4*)(p + n + i);
    float4 c = *(const float4*)(r + i);
    float4 o4;
    o4.x = a.x + b.x + c.x; o4.y = a.y + b.y + c.y;
    o4.z = a.z + b.z + c.z; o4.w = a.w + b.w + c.w;
    *(float4*)(o + i) = o4;
  }
}

// ====== merged RoPE + V-transpose (both read qkv; one launch) ======
__global__ __launch_bounds__(256) void rope_vtrans_kernel(
    const __bf16* __restrict__ qkv, __bf16* __restrict__ q_r,
    __bf16* __restrict__ k_r, __bf16* __restrict__ v_t) {
  __shared__ float cs[64], sn[64];
  __shared__ __bf16 tile[64][136];
  const int tid = threadIdx.x;
  const int bid = blockIdx.x;
  if (bid < T_SEQ) {
    const int t = bid;
    if (tid < 64) {
      float inv = exp2f(-(float)tid * (19.931568569324174f / 64.0f)); // theta=1e6
      float f = (float)t * inv;
      cs[tid] = cosf(f);
      sn[tid] = sinf(f);
    }
    __syncthreads();
    const __bf16* row = qkv + (size_t)t * QKV_N;
    for (int it = tid; it < 40 * 64; it += 256) {
      int hh = it >> 6, i = it & 63;
      float x1 = (float)row[hh * 128 + i];
      float x2 = (float)row[hh * 128 + 64 + i];
      float c = cs[i], s = sn[i];
      float o1 = x1 * c - x2 * s;
      float o2 = x2 * c + x1 * s;
      if (hh < NH) {
        __bf16* qo = q_r + (size_t)t * HIDN + hh * 128;
        qo[i] = (__bf16)o1;
        qo[64 + i] = (__bf16)o2;
      } else {
        __bf16* ko = k_r + (size_t)t * (NKV * DH) + (hh - NH) * 128;
        ko[i] = (__bf16)o1;
        ko[64 + i] = (__bf16)o2;
      }
    }
  } else {
    const int b2 = bid - T_SEQ;
    const int t0 = (b2 & 31) * 64, kh = b2 >> 5;
    #pragma unroll
    for (int i = 0; i < 4; i++) {
      int u = i * 256 + tid;
      int row = u >> 4, c = (u & 15) * 8;
      *(bf16x8*)&tile[row][c] =
          *(const bf16x8*)(qkv + (size_t)(t0 + row) * QKV_N + (NH + NKV) * DH + kh * DH + c);
    }
    __syncthreads();
    const int d = tid & 127, th = (tid >> 7) * 32;
    #pragma unroll
    for (int j = 0; j < 4; j++) {
      int t = th + j * 8;
      bf16x8 o;
      #pragma unroll
      for (int e = 0; e < 8; e++) o[e] = tile[t + e][d];
      *(bf16x8*)(v_t + ((size_t)kh * DH + d) * T_SEQ + t0 + t) = o;
    }
  }
}

// ---------------- Flash attention v2 (causal, GQA, KVB=64) ----------------
__global__ __launch_bounds__(256) void attn_kernel(
    const __bf16* __restrict__ q_r, const __bf16* __restrict__ k_r,
    const __bf16* __restrict__ v_t, __bf16* __restrict__ attn_o) {
  __shared__ __align__(16) __bf16 Ks[KVB * 128];    // 16KB
  __shared__ __align__(16) __bf16 Vs[128 * KVB];    // 16KB, rows = d
  __shared__ __align__(16) __bf16 Pl[4 * 16 * KVB]; // 8KB

  const int tid = threadIdx.x;
  const int lane = tid & 63, wv = tid >> 6;
  const int lr = lane & 15, g = lane >> 4;
  const int qt = gridDim.x - 1 - blockIdx.x;   // heavy blocks first
  const int h = blockIdx.y;
  const int kh = h >> 2;  // G = 4
  const int q0b = qt * 64;
  const int q0w = q0b + wv * 16;

  bf16x8 qf[4];
  {
    const __bf16* qp = q_r + (size_t)(q0w + lr) * HIDN + h * DH + g * 8;
    #pragma unroll
    for (int kk = 0; kk < 4; kk++) qf[kk] = *(const bf16x8*)(qp + kk * 32);
  }

  f32x4 o[8] = {};
  float mrun[4] = {-1e30f, -1e30f, -1e30f, -1e30f};
  float lrun[4] = {0.f, 0.f, 0.f, 0.f};
  char* PlW = (char*)Pl + wv * 2048;

  for (int kv0 = 0; kv0 < q0b + KVB; kv0 += KVB) {
    __syncthreads();
    #pragma unroll
    for (int i = 0; i < 4; i++) {
      int u = i * 256 + tid;
      int row = u >> 4;
      int cb = ((u & 15) * 16) ^ ((row & 7) << 4);
      glds16((const char*)(k_r + (size_t)(kv0 + row) * (NKV * DH) + kh * DH) + cb,
             (char*)Ks + u * 16);
    }
    #pragma unroll
    for (int i = 0; i < 4; i++) {
      int u = i * 256 + tid;
      int row = u >> 3;
      int cb = ((u & 7) * 16) ^ ((row & 7) << 4);
      glds16((const char*)(v_t + ((size_t)kh * DH + row) * T_SEQ + kv0) + cb,
             (char*)Vs + u * 16);
    }
    __syncthreads();

    if (q0w + 15 >= kv0) {
      f32x4 s[4] = {};
      #pragma unroll
      for (int kk = 0; kk < 4; kk++) {
        #pragma unroll
        for (int jt = 0; jt < 4; jt++) {
          int krow = jt * 16 + lr;
          int cb = (kk * 64 + g * 16) ^ ((krow & 7) << 4);
          bf16x8 kf = *(const bf16x8*)((char*)Ks + krow * 256 + cb);
          s[jt] = mfma16(qf[kk], kf, s[jt]);
        }
      }
      const bool need_mask = (kv0 + KVB - 1) > q0w;
      #pragma unroll
      for (int r = 0; r < 4; r++) {
        int qpos = q0w + g * 4 + r;
        int prow = g * 4 + r;
        float p[4];
        #pragma unroll
        for (int jt = 0; jt < 4; jt++) {
          float v = s[jt][r] * SCALE;
          if (need_mask && (kv0 + jt * 16 + lr > qpos)) v = -1e30f;
          p[jt] = v;
        }
        float mx = fmaxf(fmaxf(p[0], p[1]), fmaxf(p[2], p[3]));
        #pragma unroll
        for (int off = 1; off < 16; off <<= 1) mx = fmaxf(mx, __shfl_xor(mx, off, 64));
        float mn = fmaxf(mrun[r], mx);
        float corr = __expf(mrun[r] - mn);
        mrun[r] = mn;
        float ps = 0.f;
        #pragma unroll
        for (int jt = 0; jt < 4; jt++) {
          p[jt] = __expf(p[jt] - mn);
          ps += p[jt];
          int cbyte = ((jt * 16 + lr) * 2) ^ ((prow & 7) << 4);
          *(__bf16*)(PlW + prow * 128 + cbyte) = (__bf16)p[jt];
        }
        #pragma unroll
        for (int off = 1; off < 16; off <<= 1) ps += __shfl_xor(ps, off, 64);
        lrun[r] = lrun[r] * corr + ps;
        #pragma unroll
        for (int nt = 0; nt < 8; nt++) o[nt][r] *= corr;
      }
      bf16x8 pa[2];
      #pragma unroll
      for (int ks = 0; ks < 2; ks++)
        pa[ks] = *(const bf16x8*)(PlW + lr * 128 + ((g * 16 + ks * 64) ^ ((lr & 7) << 4)));
      #pragma unroll
      for (int nt = 0; nt < 8; nt++) {
        #pragma unroll
        for (int ks = 0; ks < 2; ks++) {
          int vrow = nt * 16 + lr;
          int cb = (ks * 64 + g * 16) ^ ((vrow & 7) << 4);
          bf16x8 vf = *(const bf16x8*)((char*)Vs + vrow * 128 + cb);
          o[nt] = mfma16(pa[ks], vf, o[nt]);
        }
      }
    }
  }

  #pragma unroll
  for (int nt = 0; nt < 8; nt++) {
    #pragma unroll
    for (int r = 0; r < 4; r++) {
      int qrow = q0w + g * 4 + r;
      int d = nt * 16 + lr;
      attn_o[(size_t)qrow * HIDN + h * DH + d] = (__bf16)(o[nt][r] / lrun[r]);
    }
  }
}

extern "C" void kernel_launch(void* const* d_in, const int* in_sizes, int n_in,
                              void* d_out, int out_size, void* d_ws, size_t ws_size,
                              hipStream_t stream) {
  const float* hidden = (const float*)d_in[0];
  const float* wqkv = (const float*)d_in[2];
  const float* wo   = (const float*)d_in[3];
  const float* w1   = (const float*)d_in[4];
  const float* w3   = (const float*)d_in[5];
  const float* w2   = (const float*)d_in[6];
  const float* anw  = (const float*)d_in[7];
  const float* fnw  = (const float*)d_in[8];

  char* ws = (char*)d_ws;
  const size_t SZ_XN   = (size_t)T_SEQ * HIDN * 2;      // 16,777,216
  const size_t SZ_QKV  = (size_t)T_SEQ * QKV_N * 2;     // 25,165,824
  const size_t SZ_KR   = (size_t)T_SEQ * NKV * DH * 2;  //  4,194,304
  const size_t SZ_H    = (size_t)T_SEQ * HIDN * 4;      // 33,554,432
  const size_t SZ_UV   = (size_t)T_SEQ * INTER * 2;     // 58,720,256

  const size_t W_QKV = (size_t)QKV_N * HIDN * 2;   // 50,331,648
  const size_t W_O   = (size_t)HIDN * HIDN * 2;    // 33,554,432
  const size_t W_I   = (size_t)INTER * HIDN * 2;   // 117,440,512
  const size_t W_TOTAL = W_QKV + W_O + 3 * W_I;    // 436,207,616

  char* act = ws + W_TOTAL;

  __bf16* xn1    = (__bf16*)(act);
  __bf16* qkv    = (__bf16*)(act + SZ_XN);
  __bf16* q_r    = (__bf16*)(act + SZ_XN + SZ_QKV);
  __bf16* gbuf   = (__bf16*)(act);                      // W13 output overlays xn1|qkv|q_r
  __bf16* k_r    = (__bf16*)(act + SZ_UV);
  __bf16* attn_o = (__bf16*)(act + SZ_UV + SZ_KR);
  float*  hbuf   = (float*) (act + SZ_UV + SZ_KR + SZ_XN);
  __bf16* v_t    = (__bf16*)(act + SZ_UV + SZ_KR + SZ_XN);  // overlays hbuf (dead until O-proj)
  __bf16* xn2    = (__bf16*)(act + SZ_UV + SZ_KR + SZ_XN + SZ_H);
  float*  pbuf   = (float*)(act + SZ_UV + SZ_KR + SZ_XN + SZ_H + SZ_XN);  // split-K partials

  __bf16* wall_b = (__bf16*)(ws);   // wqkv | wo | w13(interleaved) | w2, contiguous
  __bf16* wqkv_b = wall_b;
  __bf16* wo_b   = (__bf16*)(ws + W_QKV);
  __bf16* w13_b  = (__bf16*)(ws + W_QKV + W_O);
  __bf16* w2_b   = (__bf16*)(ws + W_QKV + W_O + 2 * W_I);

  const int LDS_BYTES = 163840;   // 5 x 32KB ring
  hipFuncSetAttribute((const void*)gemm256_kernel<0>,
                      hipFuncAttributeMaxDynamicSharedMemorySize, LDS_BYTES);
  hipFuncSetAttribute((const void*)gemm256_kernel<1>,
                      hipFuncAttributeMaxDynamicSharedMemorySize, LDS_BYTES);
  hipFuncSetAttribute((const void*)gemm256_kernel<2>,
                      hipFuncAttributeMaxDynamicSharedMemorySize, LDS_BYTES);

  cvt_all_kernel<<<2048, 256, 0, stream>>>(wqkv, wo, w1, w3, w2, wall_b);

  rmsnorm_kernel<<<T_SEQ, 256, 0, stream>>>(hidden, anw, xn1);
  // QKV: M=2048 N=6144 K=4096 -> grid 24x8 = 192 blocks
  gemm256_kernel<1><<<dim3(QKV_N / 256, T_SEQ / 256, 1), 512, LDS_BYTES, stream>>>(
      xn1, wqkv_b, qkv, T_SEQ, QKV_N, HIDN, HIDN, QKV_N);
  rope_vtrans_kernel<<<T_SEQ + 256, 256, 0, stream>>>(qkv, q_r, k_r, v_t);
  attn_kernel<<<dim3(T_SEQ / 64, NH), 256, 0, stream>>>(q_r, k_r, v_t, attn_o);
  // O-proj: split-K=2 -> 256 blocks
  gemm256_kernel<0><<<dim3(HIDN / 256, T_SEQ / 256, 2), 512, LDS_BYTES, stream>>>(
      attn_o, wo_b, pbuf, T_SEQ, HIDN, HIDN, HIDN / 2, HIDN);
  add3_rms_kernel<<<T_SEQ, 256, 0, stream>>>(pbuf, hidden, fnw, hbuf, xn2);
  // W13 fused (u|v interleaved) + silu epilogue: N=28672 -> 112x8 = 896 blocks
  gemm256_kernel<2><<<dim3(2 * INTER / 256, T_SEQ / 256, 1), 512, LDS_BYTES, stream>>>(
      xn2, w13_b, gbuf, T_SEQ, 2 * INTER, HIDN, HIDN, INTER);
  // W2: split-K=2 -> 256 blocks
  gemm256_kernel<0><<<dim3(HIDN / 256, T_SEQ / 256, 2), 512, LDS_BYTES, stream>>>(
      gbuf, w2_b, pbuf, T_SEQ, HIDN, INTER, INTER / 2, HIDN);
  add3_kernel<<<2048, 256, 0, stream>>>(pbuf, hbuf, (float*)d_out, (long)T_SEQ * HIDN);
}

// Round 14
// 1276.423 us; speedup vs baseline: 1.0212x; 1.0212x over previous
//
#include <hip/hip_runtime.h>
#include <stdint.h>

#define T_SEQ 2048
#define HIDN  4096
#define NH    32
#define NKV   8
#define DH    128
#define INTER 14336
#define QKV_N 6144   /* (32+16)*128 */
#define EPSR  1e-5f
#define SCALE 0.08838834764831845f  /* 1/sqrt(128) */
#define KVB   64

typedef __bf16 bf16x8 __attribute__((ext_vector_type(8)));
typedef float  f32x4  __attribute__((ext_vector_type(4)));

__device__ __forceinline__ f32x4 mfma16(bf16x8 a, bf16x8 b, f32x4 c) {
  return __builtin_amdgcn_mfma_f32_16x16x32_bf16(a, b, c, 0, 0, 0);
}

__device__ __forceinline__ void glds16(const void* g, void* l) {
  __builtin_amdgcn_global_load_lds(
      (__attribute__((address_space(1))) void*)g,
      (__attribute__((address_space(3))) void*)l,
      16, 0, 0);
}

// ====== merged weight convert: wqkv | wo | w13(interleaved) | w2, one kernel ======
__global__ __launch_bounds__(256) void cvt_all_kernel(
    const float* __restrict__ wqkv, const float* __restrict__ wo,
    const float* __restrict__ w1, const float* __restrict__ w3,
    const float* __restrict__ w2, __bf16* __restrict__ dst) {
  const long E0 = (long)QKV_N * HIDN;            // 25,165,824
  const long E1 = E0 + (long)HIDN * HIDN;        // 41,943,040
  const long E2 = E1 + 2L * INTER * HIDN;        // 159,383,552
  const long E3 = E2 + (long)HIDN * INTER;       // 218,103,808
  long stride = (long)gridDim.x * 256 * 16;
  for (long f = ((long)blockIdx.x * 256 + threadIdx.x) * 16; f < E3; f += stride) {
    const float* src;
    if (f < E0) {
      src = wqkv + f;
    } else if (f < E1) {
      src = wo + (f - E0);
    } else if (f < E2) {
      long l = f - E1;
      int c = (int)(l >> 12), i = (int)(l & 4095);
      int tau = c >> 8, j2 = c & 255;
      int wn = j2 >> 6, j = j2 & 63, nt = j >> 4, k16 = j & 15;
      src = (nt < 2 ? w1 : w3) +
            (size_t)(tau * 128 + wn * 32 + (nt & 1) * 16 + k16) * HIDN + i;
    } else {
      src = w2 + (f - E2);
    }
    float4 a = *(const float4*)(src);
    float4 b = *(const float4*)(src + 4);
    float4 e = *(const float4*)(src + 8);
    float4 g = *(const float4*)(src + 12);
    bf16x8 o0, o1;
    o0[0]=(__bf16)a.x; o0[1]=(__bf16)a.y; o0[2]=(__bf16)a.z; o0[3]=(__bf16)a.w;
    o0[4]=(__bf16)b.x; o0[5]=(__bf16)b.y; o0[6]=(__bf16)b.z; o0[7]=(__bf16)b.w;
    o1[0]=(__bf16)e.x; o1[1]=(__bf16)e.y; o1[2]=(__bf16)e.z; o1[3]=(__bf16)e.w;
    o1[4]=(__bf16)g.x; o1[5]=(__bf16)g.y; o1[6]=(__bf16)g.z; o1[7]=(__bf16)g.w;
    *(bf16x8*)(dst + f) = o0;
    *(bf16x8*)(dst + f + 8) = o1;
  }
}

// ---------------- RMSNorm: fp32 in -> bf16 out ----------------
__global__ __launch_bounds__(256) void rmsnorm_kernel(
    const float* __restrict__ x, const float* __restrict__ w,
    __bf16* __restrict__ y) {
  const int row = blockIdx.x, tid = threadIdx.x;
  const float* xr = x + (size_t)row * HIDN + tid * 16;
  float4 v0 = ((const float4*)xr)[0];
  float4 v1 = ((const float4*)xr)[1];
  float4 v2 = ((const float4*)xr)[2];
  float4 v3 = ((const float4*)xr)[3];
  float ss = v0.x*v0.x + v0.y*v0.y + v0.z*v0.z + v0.w*v0.w
           + v1.x*v1.x + v1.y*v1.y + v1.z*v1.z + v1.w*v1.w
           + v2.x*v2.x + v2.y*v2.y + v2.z*v2.z + v2.w*v2.w
           + v3.x*v3.x + v3.y*v3.y + v3.z*v3.z + v3.w*v3.w;
  #pragma unroll
  for (int off = 32; off >= 1; off >>= 1) ss += __shfl_xor(ss, off, 64);
  __shared__ float red[4];
  if ((tid & 63) == 0) red[tid >> 6] = ss;
  __syncthreads();
  float rn = rsqrtf((red[0] + red[1] + red[2] + red[3]) * (1.0f / HIDN) + EPSR);
  const float* wr = w + tid * 16;
  #pragma unroll
  for (int h = 0; h < 2; h++) {
    float4 a = ((const float4*)xr)[h*2], b = ((const float4*)xr)[h*2+1];
    float4 wa = ((const float4*)wr)[h*2], wb = ((const float4*)wr)[h*2+1];
    bf16x8 o;
    o[0]=(__bf16)(a.x*rn*wa.x); o[1]=(__bf16)(a.y*rn*wa.y);
    o[2]=(__bf16)(a.z*rn*wa.z); o[3]=(__bf16)(a.w*rn*wa.w);
    o[4]=(__bf16)(b.x*rn*wb.x); o[5]=(__bf16)(b.y*rn*wb.y);
    o[6]=(__bf16)(b.z*rn*wb.z); o[7]=(__bf16)(b.w*rn*wb.w);
    *(bf16x8*)(y + (size_t)row * HIDN + tid * 16 + h * 8) = o;
  }
}

// ---- fused: h = p0+p1+resid (f32 out) ; xn = rmsnorm(h)*w (bf16 out) ----
__global__ __launch_bounds__(256) void add3_rms_kernel(
    const float* __restrict__ p, const float* __restrict__ resid,
    const float* __restrict__ w, float* __restrict__ hout,
    __bf16* __restrict__ xn) {
  const int row = blockIdx.x, tid = threadIdx.x;
  const size_t base = (size_t)row * HIDN + tid * 16;
  const size_t half = (size_t)T_SEQ * HIDN;
  float h[16];
  float ss = 0.f;
  #pragma unroll
  for (int q = 0; q < 4; q++) {
    float4 a = *(const float4*)(p + base + q * 4);
    float4 b = *(const float4*)(p + half + base + q * 4);
    float4 c = *(const float4*)(resid + base + q * 4);
    h[q*4+0] = a.x + b.x + c.x; h[q*4+1] = a.y + b.y + c.y;
    h[q*4+2] = a.z + b.z + c.z; h[q*4+3] = a.w + b.w + c.w;
    ss += h[q*4]*h[q*4] + h[q*4+1]*h[q*4+1] + h[q*4+2]*h[q*4+2] + h[q*4+3]*h[q*4+3];
    *(float4*)(hout + base + q * 4) = *(float4*)&h[q*4];
  }
  #pragma unroll
  for (int off = 32; off >= 1; off >>= 1) ss += __shfl_xor(ss, off, 64);
  __shared__ float red[4];
  if ((tid & 63) == 0) red[tid >> 6] = ss;
  __syncthreads();
  float rn = rsqrtf((red[0] + red[1] + red[2] + red[3]) * (1.0f / HIDN) + EPSR);
  #pragma unroll
  for (int hb = 0; hb < 2; hb++) {
    bf16x8 o;
    #pragma unroll
    for (int e = 0; e < 8; e++) {
      float wv = w[tid * 16 + hb * 8 + e];
      o[e] = (__bf16)(h[hb*8+e] * rn * wv);
    }
    *(bf16x8*)(xn + base + hb * 8) = o;
  }
}

// ============ 256x256 8-phase GEMM v2: pipelined fragment reads ============
// (round-11/12 proven core — best measured configuration)
template<int EPI>
__global__ __launch_bounds__(512, 2) void gemm256_kernel(
    const __bf16* __restrict__ A, const __bf16* __restrict__ B,
    void* __restrict__ Cout, int M, int N, int Kfull, int KZ, int Nout) {
  extern __shared__ __align__(16) char smem[];
  const int tid = threadIdx.x;
  const int lane = tid & 63;
  const int wv = tid >> 6;        // 0..7
  const int wm = wv >> 2;         // 0..1
  const int wn = wv & 3;          // 0..3
  const int lr = lane & 15, ql = lane >> 4;

  const int gx = gridDim.x, gy = gridDim.y;
  const int nwg = gx * gy;
  const int orig = blockIdx.y * gx + blockIdx.x;
  const int cpx = nwg >> 3;
  const int swz = (orig & 7) * cpx + (orig >> 3);
  const int by = swz % gy, bx = swz / gy;
  const int m0 = by * 256, n0 = bx * 256;
  const int kbase = blockIdx.z * KZ;
  const int NT = KZ >> 6;                  // BK=64 K-tiles (even, >=32)

  const int u0 = tid, u1 = tid + 512;
  const int r0 = u0 >> 2, r1 = u1 >> 2;
  const int p0 = (u0 & 3) ^ ((r0 >> 1) & 3);
  const int p1 = (u1 & 3) ^ ((r1 >> 1) & 3);
  const char* aR0 = (const char*)(A + (size_t)(m0 + r0) * Kfull + kbase) + p0 * 16;
  const char* aR1 = (const char*)(A + (size_t)(m0 + r1) * Kfull + kbase) + p1 * 16;
  const char* bR0 = (const char*)(B + (size_t)(n0 + r0) * Kfull + kbase) + p0 * 16;
  const char* bR1 = (const char*)(B + (size_t)(n0 + r1) * Kfull + kbase) + p1 * 16;
  const int d0 = u0 * 16, d1 = u1 * 16;

  const int sA = ql ^ ((lr >> 1) & 3);
  int aoff[8], boff[4];
  #pragma unroll
  for (int mt = 0; mt < 8; mt++) aoff[mt] = (wm * 128 + mt * 16 + lr) * 64 + sA * 16;
  #pragma unroll
  for (int nt = 0; nt < 4; nt++) boff[nt] = (wn * 64 + nt * 16 + lr) * 64 + sA * 16;

#define STAGE_A(t, kh, b) do {                                         \
    const size_t _o = (size_t)(t) * 128 + (kh) * 64;                   \
    glds16(aR0 + _o, smem + (b) * 65536 + (kh) * 16384 + d0);          \
    glds16(aR1 + _o, smem + (b) * 65536 + (kh) * 16384 + d1);          \
  } while (0)
#define STAGE_B(t, kh, b) do {                                         \
    const size_t _o = (size_t)(t) * 128 + (kh) * 64;                   \
    glds16(bR0 + _o, smem + (b) * 65536 + 32768 + (kh) * 16384 + d0);  \
    glds16(bR1 + _o, smem + (b) * 65536 + 32768 + (kh) * 16384 + d1);  \
  } while (0)
#define LDA4(dst, mb, b, ks) do {                                      \
    const char* _p = smem + (b) * 65536 + (ks) * 16384;                \
    dst[0] = *(const bf16x8*)(_p + aoff[(mb) + 0]);                    \
    dst[1] = *(const bf16x8*)(_p + aoff[(mb) + 1]);                    \
    dst[2] = *(const bf16x8*)(_p + aoff[(mb) + 2]);                    \
    dst[3] = *(const bf16x8*)(_p + aoff[(mb) + 3]);                    \
  } while (0)
#define LDB4(dst, b, ks) do {                                          \
    const char* _p = smem + (b) * 65536 + 32768 + (ks) * 16384;        \
    dst[0] = *(const bf16x8*)(_p + boff[0]);                           \
    dst[1] = *(const bf16x8*)(_p + boff[1]);                           \
    dst[2] = *(const bf16x8*)(_p + boff[2]);                           \
    dst[3] = *(const bf16x8*)(_p + boff[3]);                           \
  } while (0)
#define VMW(n)  asm volatile("s_waitcnt vmcnt(" #n ")" ::: "memory")
#define BAR()   __builtin_amdgcn_s_barrier()
#define LGKM(n) do { asm volatile("s_waitcnt lgkmcnt(" #n ")" ::: "memory"); \
    __builtin_amdgcn_sched_barrier(0); } while (0)
#define MFMA16(mb, AF, BF) do {                                        \
    __builtin_amdgcn_s_setprio(1);                                     \
    _Pragma("unroll") for (int _m = 0; _m < 4; _m++)                   \
      _Pragma("unroll") for (int _n = 0; _n < 4; _n++)                 \
        acc[(mb) + _m][_n] = mfma16(AF[_m], BF[_n], acc[(mb) + _m][_n]); \
    __builtin_amdgcn_s_setprio(0);                                     \
  } while (0)

  f32x4 acc[8][4] = {};
  bf16x8 af0[4], af1[4], bf0[4], bf1[4];

  STAGE_A(0, 0, 0); STAGE_B(0, 0, 0);
  STAGE_A(0, 1, 0); STAGE_B(0, 1, 0);
  STAGE_A(1, 0, 1); STAGE_B(1, 0, 1);
  VMW(8);
  BAR();
  LDA4(af0, 0, 0, 0); LDB4(bf0, 0, 0);

  const int NI = NT >> 1;
  for (int i = 0; i < NI - 1; ++i) {
    const int t1 = 2 * i + 1, s2 = 2 * i + 2, s3 = 2 * i + 3;
    LDA4(af1, 4, 0, 0);
    STAGE_A(t1, 1, 1);
    LGKM(4);
    MFMA16(0, af0, bf0);
    VMW(6); BAR();
    LDA4(af0, 0, 0, 1); LDB4(bf1, 0, 1);
    STAGE_B(t1, 1, 1);
    LGKM(8);
    MFMA16(4, af1, bf0);
    VMW(6); BAR();
    LDA4(af1, 4, 0, 1);
    STAGE_A(s2, 0, 0);
    LGKM(4);
    MFMA16(0, af0, bf1);
    VMW(6); BAR();
    LDA4(af0, 0, 1, 0); LDB4(bf0, 1, 0);
    STAGE_B(s2, 0, 0);
    LGKM(8);
    MFMA16(4, af1, bf1);
    VMW(6); BAR();
    LDA4(af1, 4, 1, 0);
    STAGE_A(s2, 1, 0);
    LGKM(4);
    MFMA16(0, af0, bf0);
    VMW(6); BAR();
    LDA4(af0, 0, 1, 1); LDB4(bf1, 1, 1);
    STAGE_B(s2, 1, 0);
    LGKM(8);
    MFMA16(4, af1, bf0);
    VMW(6); BAR();
    LDA4(af1, 4, 1, 1);
    STAGE_A(s3, 0, 1);
    LGKM(4);
    MFMA16(0, af0, bf1);
    VMW(6); BAR();
    LDA4(af0, 0, 0, 0); LDB4(bf0, 0, 0);
    STAGE_B(s3, 0, 1);
    LGKM(8);
    MFMA16(4, af1, bf1);
    VMW(6); BAR();
  }
  {
    const int t1 = NT - 1;
    LDA4(af1, 4, 0, 0);
    STAGE_A(t1, 1, 1);
    LGKM(4);
    MFMA16(0, af0, bf0);
    VMW(6); BAR();
    LDA4(af0, 0, 0, 1); LDB4(bf1, 0, 1);
    STAGE_B(t1, 1, 1);
    LGKM(8);
    MFMA16(4, af1, bf0);
    BAR();
    LDA4(af1, 4, 0, 1);
    LGKM(4);
    MFMA16(0, af0, bf1);
    VMW(2); BAR();
    LDA4(af0, 0, 1, 0); LDB4(bf0, 1, 0);
    LGKM(8);
    MFMA16(4, af1, bf1);
    BAR();
    LDA4(af1, 4, 1, 0);
    LGKM(4);
    MFMA16(0, af0, bf0);
    VMW(0); BAR();
    LDA4(af0, 0, 1, 1); LDB4(bf1, 1, 1);
    LGKM(8);
    MFMA16(4, af1, bf0);
    BAR();
    LDA4(af1, 4, 1, 1);
    LGKM(4);
    MFMA16(0, af0, bf1);
    BAR();
    LGKM(0);
    MFMA16(4, af1, bf1);
  }

#undef STAGE_A
#undef STAGE_B
#undef LDA4
#undef LDB4
#undef VMW
#undef BAR
#undef LGKM
#undef MFMA16

  #pragma unroll
  for (int mt = 0; mt < 8; mt++) {
    #pragma unroll
    for (int r = 0; r < 4; r++) {
      int rr = m0 + wm * 128 + mt * 16 + ql * 4 + r;
      if (EPI == 2) {
        #pragma unroll
        for (int nt = 0; nt < 2; nt++) {
          float u = acc[mt][nt][r];
          float v = acc[mt][nt + 2][r];
          float g = u / (1.0f + __expf(-u)) * v;
          int cc = (n0 >> 1) + wn * 32 + nt * 16 + lr;
          ((__bf16*)Cout)[(size_t)rr * Nout + cc] = (__bf16)g;
        }
      } else {
        #pragma unroll
        for (int nt = 0; nt < 4; nt++) {
          int cc = n0 + wn * 64 + nt * 16 + lr;
          size_t ix = (size_t)rr * N + cc;
          float val = acc[mt][nt][r];
          if (EPI == 0) ((float*)Cout)[(size_t)blockIdx.z * M * N + ix] = val;
          else          ((__bf16*)Cout)[ix] = (__bf16)val;
        }
      }
    }
  }
}

// ---------------- split-K combine: out = p[0] + p[1] + resid ----------------
__global__ __launch_bounds__(256) void add3_kernel(
    const float* __restrict__ p, const float* __restrict__ r,
    float* __restrict__ o, long n) {
  long stride = (long)gridDim.x * 1024;
  for (long i = ((long)blockIdx.x * 256 + threadIdx.x) * 4; i < n; i += stride) {
    float4 a = *(const float4*)(p + i);
    float4 b = *(const float4*)(p + n + i);
    float4 c = *(const float4*)(r + i);
    float4 o4;
    o4.x = a.x + b.x + c.x; o4.y = a.y + b.y + c.y;
    o4.z = a.z + b.z + c.z; o4.w = a.w + b.w + c.w;
    *(float4*)(o + i) = o4;
  }
}

// ====== merged RoPE + V-transpose (both read qkv; one launch) ======
__global__ __launch_bounds__(256) void rope_vtrans_kernel(
    const __bf16* __restrict__ qkv, __bf16* __restrict__ q_r,
    __bf16* __restrict__ k_r, __bf16* __restrict__ v_t) {
  __shared__ float cs[64], sn[64];
  __shared__ __bf16 tile[64][136];
  const int tid = threadIdx.x;
  const int bid = blockIdx.x;
  if (bid < T_SEQ) {
    const int t = bid;
    if (tid < 64) {
      float inv = exp2f(-(float)tid * (19.931568569324174f / 64.0f)); // theta=1e6
      float f = (float)t * inv;
      cs[tid] = cosf(f);
      sn[tid] = sinf(f);
    }
    __syncthreads();
    const __bf16* row = qkv + (size_t)t * QKV_N;
    for (int it = tid; it < 40 * 64; it += 256) {
      int hh = it >> 6, i = it & 63;
      float x1 = (float)row[hh * 128 + i];
      float x2 = (float)row[hh * 128 + 64 + i];
      float c = cs[i], s = sn[i];
      float o1 = x1 * c - x2 * s;
      float o2 = x2 * c + x1 * s;
      if (hh < NH) {
        __bf16* qo = q_r + (size_t)t * HIDN + hh * 128;
        qo[i] = (__bf16)o1;
        qo[64 + i] = (__bf16)o2;
      } else {
        __bf16* ko = k_r + (size_t)t * (NKV * DH) + (hh - NH) * 128;
        ko[i] = (__bf16)o1;
        ko[64 + i] = (__bf16)o2;
      }
    }
  } else {
    const int b2 = bid - T_SEQ;
    const int t0 = (b2 & 31) * 64, kh = b2 >> 5;
    #pragma unroll
    for (int i = 0; i < 4; i++) {
      int u = i * 256 + tid;
      int row = u >> 4, c = (u & 15) * 8;
      *(bf16x8*)&tile[row][c] =
          *(const bf16x8*)(qkv + (size_t)(t0 + row) * QKV_N + (NH + NKV) * DH + kh * DH + c);
    }
    __syncthreads();
    const int d = tid & 127, th = (tid >> 7) * 32;
    #pragma unroll
    for (int j = 0; j < 4; j++) {
      int t = th + j * 8;
      bf16x8 o;
      #pragma unroll
      for (int e = 0; e < 8; e++) o[e] = tile[t + e][d];
      *(bf16x8*)(v_t + ((size_t)kh * DH + d) * T_SEQ + t0 + t) = o;
    }
  }
}

// ---------------- Flash attention v2 (causal, GQA, KVB=64) ----------------
__global__ __launch_bounds__(256) void attn_kernel(
    const __bf16* __restrict__ q_r, const __bf16* __restrict__ k_r,
    const __bf16* __restrict__ v_t, __bf16* __restrict__ attn_o) {
  __shared__ __align__(16) __bf16 Ks[KVB * 128];    // 16KB
  __shared__ __align__(16) __bf16 Vs[128 * KVB];    // 16KB, rows = d
  __shared__ __align__(16) __bf16 Pl[4 * 16 * KVB]; // 8KB

  const int tid = threadIdx.x;
  const int lane = tid & 63, wv = tid >> 6;
  const int lr = lane & 15, g = lane >> 4;
  const int qt = gridDim.x - 1 - blockIdx.x;   // heavy blocks first
  const int h = blockIdx.y;
  const int kh = h >> 2;  // G = 4
  const int q0b = qt * 64;
  const int q0w = q0b + wv * 16;

  bf16x8 qf[4];
  {
    const __bf16* qp = q_r + (size_t)(q0w + lr) * HIDN + h * DH + g * 8;
    #pragma unroll
    for (int kk = 0; kk < 4; kk++) qf[kk] = *(const bf16x8*)(qp + kk * 32);
  }

  f32x4 o[8] = {};
  float mrun[4] = {-1e30f, -1e30f, -1e30f, -1e30f};
  float lrun[4] = {0.f, 0.f, 0.f, 0.f};
  char* PlW = (char*)Pl + wv * 2048;

  for (int kv0 = 0; kv0 < q0b + KVB; kv0 += KVB) {
    __syncthreads();
    #pragma unroll
    for (int i = 0; i < 4; i++) {
      int u = i * 256 + tid;
      int row = u >> 4;
      int cb = ((u & 15) * 16) ^ ((row & 7) << 4);
      glds16((const char*)(k_r + (size_t)(kv0 + row) * (NKV * DH) + kh * DH) + cb,
             (char*)Ks + u * 16);
    }
    #pragma unroll
    for (int i = 0; i < 4; i++) {
      int u = i * 256 + tid;
      int row = u >> 3;
      int cb = ((u & 7) * 16) ^ ((row & 7) << 4);
      glds16((const char*)(v_t + ((size_t)kh * DH + row) * T_SEQ + kv0) + cb,
             (char*)Vs + u * 16);
    }
    __syncthreads();

    if (q0w + 15 >= kv0) {
      f32x4 s[4] = {};
      #pragma unroll
      for (int kk = 0; kk < 4; kk++) {
        #pragma unroll
        for (int jt = 0; jt < 4; jt++) {
          int krow = jt * 16 + lr;
          int cb = (kk * 64 + g * 16) ^ ((krow & 7) << 4);
          bf16x8 kf = *(const bf16x8*)((char*)Ks + krow * 256 + cb);
          s[jt] = mfma16(qf[kk], kf, s[jt]);
        }
      }
      const bool need_mask = (kv0 + KVB - 1) > q0w;
      #pragma unroll
      for (int r = 0; r < 4; r++) {
        int qpos = q0w + g * 4 + r;
        int prow = g * 4 + r;
        float p[4];
        #pragma unroll
        for (int jt = 0; jt < 4; jt++) {
          float v = s[jt][r] * SCALE;
          if (need_mask && (kv0 + jt * 16 + lr > qpos)) v = -1e30f;
          p[jt] = v;
        }
        float mx = fmaxf(fmaxf(p[0], p[1]), fmaxf(p[2], p[3]));
        #pragma unroll
        for (int off = 1; off < 16; off <<= 1) mx = fmaxf(mx, __shfl_xor(mx, off, 64));
        float mn = fmaxf(mrun[r], mx);
        float corr = __expf(mrun[r] - mn);
        mrun[r] = mn;
        float ps = 0.f;
        #pragma unroll
        for (int jt = 0; jt < 4; jt++) {
          p[jt] = __expf(p[jt] - mn);
          ps += p[jt];
          int cbyte = ((jt * 16 + lr) * 2) ^ ((prow & 7) << 4);
          *(__bf16*)(PlW + prow * 128 + cbyte) = (__bf16)p[jt];
        }
        #pragma unroll
        for (int off = 1; off < 16; off <<= 1) ps += __shfl_xor(ps, off, 64);
        lrun[r] = lrun[r] * corr + ps;
        #pragma unroll
        for (int nt = 0; nt < 8; nt++) o[nt][r] *= corr;
      }
      bf16x8 pa[2];
      #pragma unroll
      for (int ks = 0; ks < 2; ks++)
        pa[ks] = *(const bf16x8*)(PlW + lr * 128 + ((g * 16 + ks * 64) ^ ((lr & 7) << 4)));
      #pragma unroll
      for (int nt = 0; nt < 8; nt++) {
        #pragma unroll
        for (int ks = 0; ks < 2; ks++) {
          int vrow = nt * 16 + lr;
          int cb = (ks * 64 + g * 16) ^ ((vrow & 7) << 4);
          bf16x8 vf = *(const bf16x8*)((char*)Vs + vrow * 128 + cb);
          o[nt] = mfma16(pa[ks], vf, o[nt]);
        }
      }
    }
  }

  #pragma unroll
  for (int nt = 0; nt < 8; nt++) {
    #pragma unroll
    for (int r = 0; r < 4; r++) {
      int qrow = q0w + g * 4 + r;
      int d = nt * 16 + lr;
      attn_o[(size_t)qrow * HIDN + h * DH + d] = (__bf16)(o[nt][r] / lrun[r]);
    }
  }
}

extern "C" void kernel_launch(void* const* d_in, const int* in_sizes, int n_in,
                              void* d_out, int out_size, void* d_ws, size_t ws_size,
                              hipStream_t stream) {
  const float* hidden = (const float*)d_in[0];
  const float* wqkv = (const float*)d_in[2];
  const float* wo   = (const float*)d_in[3];
  const float* w1   = (const float*)d_in[4];
  const float* w3   = (const float*)d_in[5];
  const float* w2   = (const float*)d_in[6];
  const float* anw  = (const float*)d_in[7];
  const float* fnw  = (const float*)d_in[8];

  char* ws = (char*)d_ws;
  const size_t SZ_XN   = (size_t)T_SEQ * HIDN * 2;      // 16,777,216
  const size_t SZ_QKV  = (size_t)T_SEQ * QKV_N * 2;     // 25,165,824
  const size_t SZ_KR   = (size_t)T_SEQ * NKV * DH * 2;  //  4,194,304
  const size_t SZ_H    = (size_t)T_SEQ * HIDN * 4;      // 33,554,432
  const size_t SZ_UV   = (size_t)T_SEQ * INTER * 2;     // 58,720,256

  const size_t W_QKV = (size_t)QKV_N * HIDN * 2;   // 50,331,648
  const size_t W_O   = (size_t)HIDN * HIDN * 2;    // 33,554,432
  const size_t W_I   = (size_t)INTER * HIDN * 2;   // 117,440,512
  const size_t W_TOTAL = W_QKV + W_O + 3 * W_I;    // 436,207,616

  char* act = ws + W_TOTAL;

  __bf16* xn1    = (__bf16*)(act);
  __bf16* qkv    = (__bf16*)(act + SZ_XN);
  __bf16* q_r    = (__bf16*)(act + SZ_XN + SZ_QKV);
  __bf16* gbuf   = (__bf16*)(act);                      // W13 output overlays xn1|qkv|q_r
  __bf16* k_r    = (__bf16*)(act + SZ_UV);
  __bf16* attn_o = (__bf16*)(act + SZ_UV + SZ_KR);
  float*  hbuf   = (float*) (act + SZ_UV + SZ_KR + SZ_XN);
  __bf16* v_t    = (__bf16*)(act + SZ_UV + SZ_KR + SZ_XN);  // overlays hbuf (dead until O-proj)
  __bf16* xn2    = (__bf16*)(act + SZ_UV + SZ_KR + SZ_XN + SZ_H);
  float*  pbuf   = (float*)(act + SZ_UV + SZ_KR + SZ_XN + SZ_H + SZ_XN);  // split-K partials

  __bf16* wall_b = (__bf16*)(ws);   // wqkv | wo | w13(interleaved) | w2, contiguous
  __bf16* wqkv_b = wall_b;
  __bf16* wo_b   = (__bf16*)(ws + W_QKV);
  __bf16* w13_b  = (__bf16*)(ws + W_QKV + W_O);
  __bf16* w2_b   = (__bf16*)(ws + W_QKV + W_O + 2 * W_I);

  const int LDS_BYTES = 131072;
  hipFuncSetAttribute((const void*)gemm256_kernel<0>,
                      hipFuncAttributeMaxDynamicSharedMemorySize, LDS_BYTES);
  hipFuncSetAttribute((const void*)gemm256_kernel<1>,
                      hipFuncAttributeMaxDynamicSharedMemorySize, LDS_BYTES);
  hipFuncSetAttribute((const void*)gemm256_kernel<2>,
                      hipFuncAttributeMaxDynamicSharedMemorySize, LDS_BYTES);

  cvt_all_kernel<<<2048, 256, 0, stream>>>(wqkv, wo, w1, w3, w2, wall_b);

  rmsnorm_kernel<<<T_SEQ, 256, 0, stream>>>(hidden, anw, xn1);
  // QKV: M=2048 N=6144 K=4096 -> grid 24x8 = 192 blocks
  gemm256_kernel<1><<<dim3(QKV_N / 256, T_SEQ / 256, 1), 512, LDS_BYTES, stream>>>(
      xn1, wqkv_b, qkv, T_SEQ, QKV_N, HIDN, HIDN, QKV_N);
  rope_vtrans_kernel<<<T_SEQ + 256, 256, 0, stream>>>(qkv, q_r, k_r, v_t);
  attn_kernel<<<dim3(T_SEQ / 64, NH), 256, 0, stream>>>(q_r, k_r, v_t, attn_o);
  // O-proj: split-K=2 -> 256 blocks
  gemm256_kernel<0><<<dim3(HIDN / 256, T_SEQ / 256, 2), 512, LDS_BYTES, stream>>>(
      attn_o, wo_b, pbuf, T_SEQ, HIDN, HIDN, HIDN / 2, HIDN);
  add3_rms_kernel<<<T_SEQ, 256, 0, stream>>>(pbuf, hidden, fnw, hbuf, xn2);
  // W13 fused (u|v interleaved) + silu epilogue: N=28672 -> 112x8 = 896 blocks
  gemm256_kernel<2><<<dim3(2 * INTER / 256, T_SEQ / 256, 1), 512, LDS_BYTES, stream>>>(
      xn2, w13_b, gbuf, T_SEQ, 2 * INTER, HIDN, HIDN, INTER);
  // W2: split-K=2 -> 256 blocks
  gemm256_kernel<0><<<dim3(HIDN / 256, T_SEQ / 256, 2), 512, LDS_BYTES, stream>>>(
      gbuf, w2_b, pbuf, T_SEQ, HIDN, INTER, INTER / 2, HIDN);
  add3_kernel<<<2048, 256, 0, stream>>>(pbuf, hbuf, (float*)d_out, (long)T_SEQ * HIDN);
}